// Round 1
// baseline (115.578 us; speedup 1.0000x reference)
//
#include <hip/hip_runtime.h>

// LIF: v = v*0.5 + x_t; s = (v >= 1); v -= s
// x: (N=16, T=64, C=256, H=16, W=16) fp32 ; v_init: (N, C, H, W) fp32
// out: spikes (N, T, C, H, W) fp32

constexpr int T_STEPS  = 64;
constexpr int SPATIAL  = 256 * 16 * 16;      // C*H*W = 65536 floats per (n,t) slice
constexpr int SPAT4    = SPATIAL / 4;        // 16384 float4 per slice
constexpr int N_BATCH  = 16;

__global__ __launch_bounds__(256)
void lif_kernel(const float4* __restrict__ x,
                const float4* __restrict__ v_init,
                float4* __restrict__ out)
{
    const int gid = blockIdx.x * blockDim.x + threadIdx.x;  // float4 index over (N, SPAT4)
    const int n   = gid >> 14;        // gid / 16384
    const int s4  = gid & (SPAT4 - 1);

    // all offsets in float4 units; max = 16*64*16384 = 16.7M -> fits int32
    const int nbase = n * (T_STEPS * SPAT4);

    float4 v = v_init[n * SPAT4 + s4];

    #pragma unroll
    for (int t = 0; t < T_STEPS; ++t) {
        const int off = nbase + t * SPAT4 + s4;
        const float4 xt = x[off];
        float4 s;
        v.x = v.x * 0.5f + xt.x;  s.x = (v.x >= 1.0f) ? 1.0f : 0.0f;  v.x -= s.x;
        v.y = v.y * 0.5f + xt.y;  s.y = (v.y >= 1.0f) ? 1.0f : 0.0f;  v.y -= s.y;
        v.z = v.z * 0.5f + xt.z;  s.z = (v.z >= 1.0f) ? 1.0f : 0.0f;  v.z -= s.z;
        v.w = v.w * 0.5f + xt.w;  s.w = (v.w >= 1.0f) ? 1.0f : 0.0f;  v.w -= s.w;
        out[off] = s;
    }
}

extern "C" void kernel_launch(void* const* d_in, const int* in_sizes, int n_in,
                              void* d_out, int out_size, void* d_ws, size_t ws_size,
                              hipStream_t stream)
{
    const float4* x      = (const float4*)d_in[0];
    const float4* v_init = (const float4*)d_in[1];
    float4*       out    = (float4*)d_out;

    const int total4 = N_BATCH * SPAT4;          // 262144 threads
    const int block  = 256;
    const int grid   = total4 / block;           // 1024 blocks

    lif_kernel<<<grid, block, 0, stream>>>(x, v_init, out);
}